// Round 2
// baseline (81.692 us; speedup 1.0000x reference)
//
#include <hip/hip_runtime.h>
#include <hip/hip_bf16.h>
#include <math.h>

// Problem: x, y fp32 [NT=5000, 512, 16] -> scalar
//   per column c (of 8192): sxx=sum x^2, syy=sum y^2, sxy=sum x*y, mx=max|x|
//   cc = -0.001*sxy/((sqrt(sxx)+1e-10)*(sqrt(syy)+1e-10)); out = sum(cc where mx>0)

#define NT_TOTAL 5000
#define NCOL     8192          // 512*16, contiguous inner dims

// Phase 1: per-chunk, per-column partial reductions.
// grid = (32 col-blocks, nchunk); block = 256 threads; one scalar column per thread.
// 1600 blocks = 6400 waves -> ~78% occupancy (latency hiding).
__global__ __launch_bounds__(256) void ncc_partial(const float* __restrict__ x,
                                                   const float* __restrict__ y,
                                                   float* __restrict__ ws,
                                                   int clen, int nchunk) {
    const int c  = blockIdx.x * 256 + threadIdx.x;   // 0..8191
    const int ch = blockIdx.y;
    int n0 = ch * clen;
    int n1 = n0 + clen;
    if (n1 > NT_TOTAL) n1 = NT_TOTAL;
    const int steps = n1 - n0;

    const float* xp = x + (size_t)n0 * NCOL + c;
    const float* yp = y + (size_t)n0 * NCOL + c;

    float sxx = 0.f, syy = 0.f, sxy = 0.f, mx = 0.f;

    int i = 0;
    // 4-wide manual batch: 8 loads issued before first use -> deep VMEM pipeline
    for (; i + 4 <= steps; i += 4) {
        float a0 = xp[0];
        float a1 = xp[NCOL];
        float a2 = xp[2 * NCOL];
        float a3 = xp[3 * NCOL];
        float b0 = yp[0];
        float b1 = yp[NCOL];
        float b2 = yp[2 * NCOL];
        float b3 = yp[3 * NCOL];
        xp += 4 * NCOL;
        yp += 4 * NCOL;
        sxx = fmaf(a0, a0, sxx); syy = fmaf(b0, b0, syy); sxy = fmaf(a0, b0, sxy);
        mx  = fmaxf(mx, fabsf(a0));
        sxx = fmaf(a1, a1, sxx); syy = fmaf(b1, b1, syy); sxy = fmaf(a1, b1, sxy);
        mx  = fmaxf(mx, fabsf(a1));
        sxx = fmaf(a2, a2, sxx); syy = fmaf(b2, b2, syy); sxy = fmaf(a2, b2, sxy);
        mx  = fmaxf(mx, fabsf(a2));
        sxx = fmaf(a3, a3, sxx); syy = fmaf(b3, b3, syy); sxy = fmaf(a3, b3, sxy);
        mx  = fmaxf(mx, fabsf(a3));
    }
    for (; i < steps; ++i) {
        float a = xp[0];
        float b = yp[0];
        xp += NCOL;
        yp += NCOL;
        sxx = fmaf(a, a, sxx); syy = fmaf(b, b, syy); sxy = fmaf(a, b, sxy);
        mx  = fmaxf(mx, fabsf(a));
    }

    // ws layout (floats): [4 kinds][nchunk][NCOL]
    float* SXX = ws;
    float* SYY = ws + (size_t)nchunk * NCOL;
    float* SXY = ws + (size_t)2 * nchunk * NCOL;
    float* MX  = ws + (size_t)3 * nchunk * NCOL;
    const size_t idx = (size_t)ch * NCOL + c;
    SXX[idx] = sxx;
    SYY[idx] = syy;
    SXY[idx] = sxy;
    MX[idx]  = mx;
}

// Phase 2: combine chunks per column (float4 over columns), apply nonlinearity
// + mask, reduce to one partial per block. grid = 32 blocks x 64 threads
// (2048 threads x 4 cols = 8192 cols), spread over 32 CUs.
__global__ __launch_bounds__(64) void ncc_combine(const float4* __restrict__ ws4,
                                                  float* __restrict__ partials,
                                                  int nchunk) {
    const int c4 = blockIdx.x * 64 + threadIdx.x;   // 0..2047 (float4 column group)
    const int NC4 = NCOL / 4;
    const float4* SXX = ws4;
    const float4* SYY = ws4 + (size_t)nchunk * NC4;
    const float4* SXY = ws4 + (size_t)2 * nchunk * NC4;
    const float4* MX  = ws4 + (size_t)3 * nchunk * NC4;

    float4 sxx = make_float4(0.f, 0.f, 0.f, 0.f);
    float4 syy = make_float4(0.f, 0.f, 0.f, 0.f);
    float4 sxy = make_float4(0.f, 0.f, 0.f, 0.f);
    float4 mx  = make_float4(0.f, 0.f, 0.f, 0.f);
    for (int ch = 0; ch < nchunk; ++ch) {
        const size_t idx = (size_t)ch * NC4 + c4;
        float4 a = SXX[idx], b = SYY[idx], d = SXY[idx], m = MX[idx];
        sxx.x += a.x; sxx.y += a.y; sxx.z += a.z; sxx.w += a.w;
        syy.x += b.x; syy.y += b.y; syy.z += b.z; syy.w += b.w;
        sxy.x += d.x; sxy.y += d.y; sxy.z += d.z; sxy.w += d.w;
        mx.x = fmaxf(mx.x, m.x); mx.y = fmaxf(mx.y, m.y);
        mx.z = fmaxf(mx.z, m.z); mx.w = fmaxf(mx.w, m.w);
    }

    float cc = 0.f;
    if (mx.x > 0.f) cc += -0.001f * sxy.x / ((sqrtf(sxx.x) + 1e-10f) * (sqrtf(syy.x) + 1e-10f));
    if (mx.y > 0.f) cc += -0.001f * sxy.y / ((sqrtf(sxx.y) + 1e-10f) * (sqrtf(syy.y) + 1e-10f));
    if (mx.z > 0.f) cc += -0.001f * sxy.z / ((sqrtf(sxx.z) + 1e-10f) * (sqrtf(syy.z) + 1e-10f));
    if (mx.w > 0.f) cc += -0.001f * sxy.w / ((sqrtf(sxx.w) + 1e-10f) * (sqrtf(syy.w) + 1e-10f));

    // single-wave shuffle reduce
    for (int off = 32; off > 0; off >>= 1)
        cc += __shfl_down(cc, off);
    if (threadIdx.x == 0)
        partials[blockIdx.x] = cc;
}

// Phase 3: sum 32 block partials -> scalar.
__global__ __launch_bounds__(64) void ncc_final(const float* __restrict__ partials,
                                                float* __restrict__ out) {
    float v = (threadIdx.x < 32) ? partials[threadIdx.x] : 0.f;
    for (int off = 32; off > 0; off >>= 1)
        v += __shfl_down(v, off);
    if (threadIdx.x == 0) out[0] = v;
}

extern "C" void kernel_launch(void* const* d_in, const int* in_sizes, int n_in,
                              void* d_out, int out_size, void* d_ws, size_t ws_size,
                              hipStream_t stream) {
    const float* x = (const float*)d_in[0];
    const float* y = (const float*)d_in[1];
    float* out = (float*)d_out;
    float* ws  = (float*)d_ws;

    // Choose chunk count to fit workspace: 4 arrays * nchunk * NCOL floats + 32 partials.
    const size_t per_chunk_bytes = 4ull * NCOL * sizeof(float);  // 128 KiB
    size_t avail = (ws_size > 256) ? (ws_size - 256) : 0;
    int nchunk = (int)(avail / per_chunk_bytes);
    if (nchunk > 50) nchunk = 50;
    if (nchunk < 1)  nchunk = 1;   // degenerate fallback; needs >=128KiB ws
    const int clen = (NT_TOTAL + nchunk - 1) / nchunk;

    float* partials = ws + 4ull * (size_t)nchunk * NCOL;

    dim3 g1(NCOL / 256, nchunk);   // (32, nchunk)
    ncc_partial<<<g1, 256, 0, stream>>>(x, y, ws, clen, nchunk);
    ncc_combine<<<32, 64, 0, stream>>>((const float4*)ws, partials, nchunk);
    ncc_final<<<1, 64, 0, stream>>>(partials, out);
}

// Round 3
// 78.219 us; speedup vs baseline: 1.0444x; 1.0444x over previous
//
#include <hip/hip_runtime.h>
#include <hip/hip_bf16.h>
#include <math.h>

// Problem: x, y fp32 [NT=5000, 512, 16] -> scalar
//   per column c (of 8192): sxx=sum x^2, syy=sum y^2, sxy=sum x*y, mx=max|x|
//   cc = -0.001*sxy/((sqrt(sxx)+1e-10)*(sqrt(syy)+1e-10)); out = sum(cc where mx>0)

#define NT_TOTAL 5000
#define NCOL     8192          // 512*16, contiguous inner dims
#define NCOL4    2048          // NCOL/4

// ---------------------------------------------------------------------------
// Phase 1: per-chunk, per-column partial reductions.
// grid = (8 col4-blocks, nchunk); block = 256; each thread owns 4 columns.
// 8-step batch => 16 independent global_load_dwordx4 in flight (~16KB/wave)
// before the first use -> deep VMEM pipeline (in-flight-bytes bound fix).
// ---------------------------------------------------------------------------
__global__ __launch_bounds__(256) void ncc_partial(const float4* __restrict__ x,
                                                   const float4* __restrict__ y,
                                                   float4* __restrict__ ws,
                                                   int clen, int nchunk) {
    const int col4 = blockIdx.x * 256 + threadIdx.x;   // 0..2047
    const int ch   = blockIdx.y;
    int n0 = ch * clen;
    int n1 = n0 + clen;
    if (n1 > NT_TOTAL) n1 = NT_TOTAL;
    const int steps = (n1 > n0) ? (n1 - n0) : 0;

    const float4* xp = x + (size_t)n0 * NCOL4 + col4;
    const float4* yp = y + (size_t)n0 * NCOL4 + col4;

    float4 sxx = make_float4(0.f, 0.f, 0.f, 0.f);
    float4 syy = make_float4(0.f, 0.f, 0.f, 0.f);
    float4 sxy = make_float4(0.f, 0.f, 0.f, 0.f);
    float4 mx  = make_float4(0.f, 0.f, 0.f, 0.f);

#define ACC(a, b)                                                     \
    sxx.x = fmaf(a.x, a.x, sxx.x); sxx.y = fmaf(a.y, a.y, sxx.y);     \
    sxx.z = fmaf(a.z, a.z, sxx.z); sxx.w = fmaf(a.w, a.w, sxx.w);     \
    syy.x = fmaf(b.x, b.x, syy.x); syy.y = fmaf(b.y, b.y, syy.y);     \
    syy.z = fmaf(b.z, b.z, syy.z); syy.w = fmaf(b.w, b.w, syy.w);     \
    sxy.x = fmaf(a.x, b.x, sxy.x); sxy.y = fmaf(a.y, b.y, sxy.y);     \
    sxy.z = fmaf(a.z, b.z, sxy.z); sxy.w = fmaf(a.w, b.w, sxy.w);     \
    mx.x = fmaxf(mx.x, fabsf(a.x)); mx.y = fmaxf(mx.y, fabsf(a.y));   \
    mx.z = fmaxf(mx.z, fabsf(a.z)); mx.w = fmaxf(mx.w, fabsf(a.w))

    int i = 0;
    for (; i + 8 <= steps; i += 8) {
        // 16 independent loads, all issued before any consumer
        float4 a0 = xp[0 * NCOL4];
        float4 a1 = xp[1 * NCOL4];
        float4 a2 = xp[2 * NCOL4];
        float4 a3 = xp[3 * NCOL4];
        float4 a4 = xp[4 * NCOL4];
        float4 a5 = xp[5 * NCOL4];
        float4 a6 = xp[6 * NCOL4];
        float4 a7 = xp[7 * NCOL4];
        float4 b0 = yp[0 * NCOL4];
        float4 b1 = yp[1 * NCOL4];
        float4 b2 = yp[2 * NCOL4];
        float4 b3 = yp[3 * NCOL4];
        float4 b4 = yp[4 * NCOL4];
        float4 b5 = yp[5 * NCOL4];
        float4 b6 = yp[6 * NCOL4];
        float4 b7 = yp[7 * NCOL4];
        xp += 8 * NCOL4;
        yp += 8 * NCOL4;
        ACC(a0, b0); ACC(a1, b1); ACC(a2, b2); ACC(a3, b3);
        ACC(a4, b4); ACC(a5, b5); ACC(a6, b6); ACC(a7, b7);
    }
    for (; i < steps; ++i) {
        float4 a = xp[0];
        float4 b = yp[0];
        xp += NCOL4;
        yp += NCOL4;
        ACC(a, b);
    }
#undef ACC

    // ws layout (float4 units): [4 kinds][nchunk][NCOL4]
    float4* SXX = ws;
    float4* SYY = ws + (size_t)nchunk * NCOL4;
    float4* SXY = ws + (size_t)2 * nchunk * NCOL4;
    float4* MX  = ws + (size_t)3 * nchunk * NCOL4;
    const size_t idx = (size_t)ch * NCOL4 + col4;
    SXX[idx] = sxx;
    SYY[idx] = syy;
    SXY[idx] = sxy;
    MX[idx]  = mx;
}

// ---------------------------------------------------------------------------
// Phase 2: combine chunks per column, nonlinearity + mask, reduce per block.
// grid = 32 blocks x 256 threads. Thread tx: c4 = blk*64 + (tx&63),
// chunk-strip = tx>>6 (4 strips) -> 4x parallel over the chunk loop,
// LDS-combined, then one wave does the nonlinearity + reduce.
// ---------------------------------------------------------------------------
__global__ __launch_bounds__(256) void ncc_combine(const float4* __restrict__ ws4,
                                                   float* __restrict__ partials,
                                                   int nchunk) {
    const int lane  = threadIdx.x & 63;
    const int strip = threadIdx.x >> 6;          // 0..3
    const int c4    = blockIdx.x * 64 + lane;    // 0..2047
    const int NC4   = NCOL4;

    const float4* SXX = ws4;
    const float4* SYY = ws4 + (size_t)nchunk * NC4;
    const float4* SXY = ws4 + (size_t)2 * nchunk * NC4;
    const float4* MX  = ws4 + (size_t)3 * nchunk * NC4;

    const int spc = (nchunk + 3) / 4;
    int ch0 = strip * spc;
    int ch1 = ch0 + spc;
    if (ch1 > nchunk) ch1 = nchunk;

    float4 sxx = make_float4(0.f, 0.f, 0.f, 0.f);
    float4 syy = make_float4(0.f, 0.f, 0.f, 0.f);
    float4 sxy = make_float4(0.f, 0.f, 0.f, 0.f);
    float4 mx  = make_float4(0.f, 0.f, 0.f, 0.f);
    for (int ch = ch0; ch < ch1; ++ch) {
        const size_t idx = (size_t)ch * NC4 + c4;
        float4 a = SXX[idx], b = SYY[idx], d = SXY[idx], m = MX[idx];
        sxx.x += a.x; sxx.y += a.y; sxx.z += a.z; sxx.w += a.w;
        syy.x += b.x; syy.y += b.y; syy.z += b.z; syy.w += b.w;
        sxy.x += d.x; sxy.y += d.y; sxy.z += d.z; sxy.w += d.w;
        mx.x = fmaxf(mx.x, m.x); mx.y = fmaxf(mx.y, m.y);
        mx.z = fmaxf(mx.z, m.z); mx.w = fmaxf(mx.w, m.w);
    }

    __shared__ float4 LXX[4][64], LYY[4][64], LXY[4][64], LMX[4][64];
    LXX[strip][lane] = sxx;
    LYY[strip][lane] = syy;
    LXY[strip][lane] = sxy;
    LMX[strip][lane] = mx;
    __syncthreads();

    if (strip == 0) {
        for (int s = 1; s < 4; ++s) {
            float4 a = LXX[s][lane], b = LYY[s][lane], d = LXY[s][lane], m = LMX[s][lane];
            sxx.x += a.x; sxx.y += a.y; sxx.z += a.z; sxx.w += a.w;
            syy.x += b.x; syy.y += b.y; syy.z += b.z; syy.w += b.w;
            sxy.x += d.x; sxy.y += d.y; sxy.z += d.z; sxy.w += d.w;
            mx.x = fmaxf(mx.x, m.x); mx.y = fmaxf(mx.y, m.y);
            mx.z = fmaxf(mx.z, m.z); mx.w = fmaxf(mx.w, m.w);
        }
        float cc = 0.f;
        if (mx.x > 0.f) cc += -0.001f * sxy.x / ((sqrtf(sxx.x) + 1e-10f) * (sqrtf(syy.x) + 1e-10f));
        if (mx.y > 0.f) cc += -0.001f * sxy.y / ((sqrtf(sxx.y) + 1e-10f) * (sqrtf(syy.y) + 1e-10f));
        if (mx.z > 0.f) cc += -0.001f * sxy.z / ((sqrtf(sxx.z) + 1e-10f) * (sqrtf(syy.z) + 1e-10f));
        if (mx.w > 0.f) cc += -0.001f * sxy.w / ((sqrtf(sxx.w) + 1e-10f) * (sqrtf(syy.w) + 1e-10f));

        for (int off = 32; off > 0; off >>= 1)
            cc += __shfl_down(cc, off);
        if (lane == 0)
            partials[blockIdx.x] = cc;
    }
}

// Phase 3: sum 32 block partials -> scalar.
__global__ __launch_bounds__(64) void ncc_final(const float* __restrict__ partials,
                                                float* __restrict__ out) {
    float v = (threadIdx.x < 32) ? partials[threadIdx.x] : 0.f;
    for (int off = 32; off > 0; off >>= 1)
        v += __shfl_down(v, off);
    if (threadIdx.x == 0) out[0] = v;
}

extern "C" void kernel_launch(void* const* d_in, const int* in_sizes, int n_in,
                              void* d_out, int out_size, void* d_ws, size_t ws_size,
                              hipStream_t stream) {
    const float* x = (const float*)d_in[0];
    const float* y = (const float*)d_in[1];
    float* out = (float*)d_out;
    float* ws  = (float*)d_ws;

    // Workspace: 4 arrays * nchunk * NCOL floats + 32 partials.
    const size_t per_chunk_bytes = 4ull * NCOL * sizeof(float);  // 128 KiB
    size_t avail = (ws_size > 256) ? (ws_size - 256) : 0;
    int nchunk = (int)(avail / per_chunk_bytes);
    if (nchunk > 100) nchunk = 100;
    if (nchunk < 1)   nchunk = 1;   // degenerate fallback; needs >=128KiB ws
    const int clen = (NT_TOTAL + nchunk - 1) / nchunk;

    float* partials = ws + 4ull * (size_t)nchunk * NCOL;

    dim3 g1(NCOL4 / 256, nchunk);   // (8, nchunk)
    ncc_partial<<<g1, 256, 0, stream>>>((const float4*)x, (const float4*)y,
                                        (float4*)ws, clen, nchunk);
    ncc_combine<<<32, 256, 0, stream>>>((const float4*)ws, partials, nchunk);
    ncc_final<<<1, 64, 0, stream>>>(partials, out);
}

// Round 4
// 67.384 us; speedup vs baseline: 1.2123x; 1.1608x over previous
//
#include <hip/hip_runtime.h>
#include <hip/hip_bf16.h>
#include <math.h>

// Problem: x, y fp32 [NT=5000, 512, 16] -> scalar
//   per column c (of 8192): sxx=sum x^2, syy=sum y^2, sxy=sum x*y, mx=max|x|
//   cc = -0.001*sxy/((sqrt(sxx)+1e-10)*(sqrt(syy)+1e-10)); out = sum(cc where mx>0)

#define NT       5000
#define NROW_F   8192          // floats per time row (512*16)
#define NCOL     8192
#define NCOL4    2048

typedef __attribute__((address_space(3))) void lds_void;
typedef const __attribute__((address_space(1))) void gm_void;

// ---------------------------------------------------------------------------
// Phase 1: wave-independent global_load_lds pipeline.
// grid = (8 col-tiles, nchunk); block = 256 (4 waves). Each wave owns a
// private region of two distinct LDS buffers (A/B), double-buffered tiles of
// 4 rows. Per tile: 8 x global_load_lds_dwordx4 (1KB each) fire-and-forget,
// counted s_waitcnt vmcnt(8) (never 0 mid-loop), ds_read_b128 consume.
// No __syncthreads in the loop -> no forced vmcnt(0) drains.
// In-flight ~16KB/wave * 8 waves/CU >> latency-BW product (~18KB/CU).
// ---------------------------------------------------------------------------
__global__ __launch_bounds__(256) void ncc_partial(const float* __restrict__ xg,
                                                   const float* __restrict__ yg,
                                                   float4* __restrict__ ws,
                                                   int clen, int nchunk, int T) {
    // [wave][row][x/y][64 lanes] float4 = 32 KiB each; distinct arrays so the
    // compiler can disambiguate ds_read(A) from outstanding LDS-DMA into B.
    __shared__ float4 BA[4][4][2][64];
    __shared__ float4 BB[4][4][2][64];

    const int tid  = threadIdx.x;
    const int w    = tid >> 6;
    const int lane = tid & 63;
    const int bx   = blockIdx.x;        // 0..7 col-tile (1024 floats each)
    const int ch   = blockIdx.y;
    const int n0   = ch * clen;
    int n1 = n0 + clen; if (n1 > NT) n1 = NT;

    const int colf = bx * 1024 + tid * 4;   // first float column of this thread

    float4 sxx = make_float4(0.f, 0.f, 0.f, 0.f);
    float4 syy = make_float4(0.f, 0.f, 0.f, 0.f);
    float4 sxy = make_float4(0.f, 0.f, 0.f, 0.f);
    float4 mx  = make_float4(0.f, 0.f, 0.f, 0.f);

#define ACC4(a, b)                                                      \
    sxx.x = fmaf(a.x, a.x, sxx.x); sxx.y = fmaf(a.y, a.y, sxx.y);       \
    sxx.z = fmaf(a.z, a.z, sxx.z); sxx.w = fmaf(a.w, a.w, sxx.w);       \
    syy.x = fmaf(b.x, b.x, syy.x); syy.y = fmaf(b.y, b.y, syy.y);       \
    syy.z = fmaf(b.z, b.z, syy.z); syy.w = fmaf(b.w, b.w, syy.w);       \
    sxy.x = fmaf(a.x, b.x, sxy.x); sxy.y = fmaf(a.y, b.y, sxy.y);       \
    sxy.z = fmaf(a.z, b.z, sxy.z); sxy.w = fmaf(a.w, b.w, sxy.w);       \
    mx.x = fmaxf(mx.x, fabsf(a.x)); mx.y = fmaxf(mx.y, fabsf(a.y));     \
    mx.z = fmaxf(mx.z, fabsf(a.z)); mx.w = fmaxf(mx.w, fabsf(a.w))

    // Issue 8 DMA loads (4 rows x {x,y}) for tile t into BUF's wave region.
    // Row index clamped (safe address); accumulation is predicated instead.
#define ISSUE(BUF, t)                                                         \
    {                                                                         \
        _Pragma("unroll")                                                     \
        for (int r = 0; r < 4; ++r) {                                         \
            int n = n0 + (t) * 4 + r;                                         \
            if (n > NT - 1) n = NT - 1;                                       \
            const float* px = xg + (size_t)n * NROW_F + colf;                 \
            const float* py = yg + (size_t)n * NROW_F + colf;                 \
            __builtin_amdgcn_global_load_lds((gm_void*)px,                    \
                (lds_void*)&BUF[w][r][0][0], 16, 0, 0);                       \
            __builtin_amdgcn_global_load_lds((gm_void*)py,                    \
                (lds_void*)&BUF[w][r][1][0], 16, 0, 0);                       \
        }                                                                     \
    }

#define COMPUTE(BUF, t)                                                       \
    {                                                                         \
        _Pragma("unroll")                                                     \
        for (int r = 0; r < 4; ++r) {                                         \
            float4 a = BUF[w][r][0][lane];                                    \
            float4 b = BUF[w][r][1][lane];                                    \
            int n = n0 + (t) * 4 + r;                                         \
            if (n < n1) { ACC4(a, b); }                                       \
        }                                                                     \
    }

#define WAITV(N)                                                              \
    asm volatile("s_waitcnt vmcnt(" #N ")" ::: "memory");                     \
    __builtin_amdgcn_sched_barrier(0)

#define WAITL()                                                               \
    asm volatile("s_waitcnt lgkmcnt(0)" ::: "memory");                        \
    __builtin_amdgcn_sched_barrier(0)

    // T is even and >= 2 (host guarantees). Tiles 0..T-1.
    ISSUE(BA, 0);
    ISSUE(BB, 1);
    for (int t = 0; t + 4 <= T; t += 2) {
        WAITV(8);                // tile t landed (t+1 still in flight)
        COMPUTE(BA, t);
        WAITL();                 // ds_reads of BA drained before overwrite
        ISSUE(BA, t + 2);
        WAITV(8);                // tile t+1 landed (t+2 in flight)
        COMPUTE(BB, t + 1);
        WAITL();
        ISSUE(BB, t + 3);
    }
    WAITV(8);
    COMPUTE(BA, T - 2);
    WAITV(0);
    COMPUTE(BB, T - 1);

#undef ACC4
#undef ISSUE
#undef COMPUTE
#undef WAITV
#undef WAITL

    // ws layout (float4 units): [4 kinds][nchunk][NCOL4]
    float4* SXX = ws;
    float4* SYY = ws + (size_t)nchunk * NCOL4;
    float4* SXY = ws + (size_t)2 * nchunk * NCOL4;
    float4* MX  = ws + (size_t)3 * nchunk * NCOL4;
    const size_t idx = (size_t)ch * NCOL4 + bx * 256 + tid;
    SXX[idx] = sxx;
    SYY[idx] = syy;
    SXY[idx] = sxy;
    MX[idx]  = mx;
}

// ---------------------------------------------------------------------------
// Phase 2: combine chunks per column, nonlinearity + mask, reduce per block.
// grid = 32 blocks x 256 threads; 4 chunk-strips per block, LDS-combined.
// ---------------------------------------------------------------------------
__global__ __launch_bounds__(256) void ncc_combine(const float4* __restrict__ ws4,
                                                   float* __restrict__ partials,
                                                   int nchunk) {
    const int lane  = threadIdx.x & 63;
    const int strip = threadIdx.x >> 6;          // 0..3
    const int c4    = blockIdx.x * 64 + lane;    // 0..2047

    const float4* SXX = ws4;
    const float4* SYY = ws4 + (size_t)nchunk * NCOL4;
    const float4* SXY = ws4 + (size_t)2 * nchunk * NCOL4;
    const float4* MX  = ws4 + (size_t)3 * nchunk * NCOL4;

    const int spc = (nchunk + 3) / 4;
    int ch0 = strip * spc;
    int ch1 = ch0 + spc;
    if (ch1 > nchunk) ch1 = nchunk;

    float4 sxx = make_float4(0.f, 0.f, 0.f, 0.f);
    float4 syy = make_float4(0.f, 0.f, 0.f, 0.f);
    float4 sxy = make_float4(0.f, 0.f, 0.f, 0.f);
    float4 mx  = make_float4(0.f, 0.f, 0.f, 0.f);
    for (int ch = ch0; ch < ch1; ++ch) {
        const size_t idx = (size_t)ch * NCOL4 + c4;
        float4 a = SXX[idx], b = SYY[idx], d = SXY[idx], m = MX[idx];
        sxx.x += a.x; sxx.y += a.y; sxx.z += a.z; sxx.w += a.w;
        syy.x += b.x; syy.y += b.y; syy.z += b.z; syy.w += b.w;
        sxy.x += d.x; sxy.y += d.y; sxy.z += d.z; sxy.w += d.w;
        mx.x = fmaxf(mx.x, m.x); mx.y = fmaxf(mx.y, m.y);
        mx.z = fmaxf(mx.z, m.z); mx.w = fmaxf(mx.w, m.w);
    }

    __shared__ float4 LXX[4][64], LYY[4][64], LXY[4][64], LMX[4][64];
    LXX[strip][lane] = sxx;
    LYY[strip][lane] = syy;
    LXY[strip][lane] = sxy;
    LMX[strip][lane] = mx;
    __syncthreads();

    if (strip == 0) {
        for (int s = 1; s < 4; ++s) {
            float4 a = LXX[s][lane], b = LYY[s][lane], d = LXY[s][lane], m = LMX[s][lane];
            sxx.x += a.x; sxx.y += a.y; sxx.z += a.z; sxx.w += a.w;
            syy.x += b.x; syy.y += b.y; syy.z += b.z; syy.w += b.w;
            sxy.x += d.x; sxy.y += d.y; sxy.z += d.z; sxy.w += d.w;
            mx.x = fmaxf(mx.x, m.x); mx.y = fmaxf(mx.y, m.y);
            mx.z = fmaxf(mx.z, m.z); mx.w = fmaxf(mx.w, m.w);
        }
        float cc = 0.f;
        if (mx.x > 0.f) cc += -0.001f * sxy.x / ((sqrtf(sxx.x) + 1e-10f) * (sqrtf(syy.x) + 1e-10f));
        if (mx.y > 0.f) cc += -0.001f * sxy.y / ((sqrtf(sxx.y) + 1e-10f) * (sqrtf(syy.y) + 1e-10f));
        if (mx.z > 0.f) cc += -0.001f * sxy.z / ((sqrtf(sxx.z) + 1e-10f) * (sqrtf(syy.z) + 1e-10f));
        if (mx.w > 0.f) cc += -0.001f * sxy.w / ((sqrtf(sxx.w) + 1e-10f) * (sqrtf(syy.w) + 1e-10f));

        for (int off = 32; off > 0; off >>= 1)
            cc += __shfl_down(cc, off);
        if (lane == 0)
            partials[blockIdx.x] = cc;
    }
}

// Phase 3: sum 32 block partials -> scalar.
__global__ __launch_bounds__(64) void ncc_final(const float* __restrict__ partials,
                                                float* __restrict__ out) {
    float v = (threadIdx.x < 32) ? partials[threadIdx.x] : 0.f;
    for (int off = 32; off > 0; off >>= 1)
        v += __shfl_down(v, off);
    if (threadIdx.x == 0) out[0] = v;
}

extern "C" void kernel_launch(void* const* d_in, const int* in_sizes, int n_in,
                              void* d_out, int out_size, void* d_ws, size_t ws_size,
                              hipStream_t stream) {
    const float* x = (const float*)d_in[0];
    const float* y = (const float*)d_in[1];
    float* out = (float*)d_out;
    float* ws  = (float*)d_ws;

    // Workspace: 4 arrays * nchunk * NCOL floats + 32 partials.
    const size_t per_chunk_bytes = 4ull * NCOL * sizeof(float);  // 128 KiB
    size_t avail = (ws_size > 256) ? (ws_size - 256) : 0;
    int nchunk = (int)(avail / per_chunk_bytes);
    if (nchunk > 64) nchunk = 64;   // 8 col-tiles * 64 = 512 blocks = 2/CU
    if (nchunk < 1)  nchunk = 1;
    const int clen = (NT + nchunk - 1) / nchunk;

    int T = (clen + 3) / 4;         // 4-row tiles per chunk
    if (T & 1) T++;                 // even T (loop structure); extra tile is
    if (T < 2) T = 2;               // fully predicated off (clamped loads)

    float* partials = ws + 4ull * (size_t)nchunk * NCOL;

    dim3 g1(8, nchunk);
    ncc_partial<<<g1, 256, 0, stream>>>(x, y, (float4*)ws, clen, nchunk, T);
    ncc_combine<<<32, 256, 0, stream>>>((const float4*)ws, partials, nchunk);
    ncc_final<<<1, 64, 0, stream>>>(partials, out);
}